// Round 17
// baseline (110.430 us; speedup 1.0000x reference)
//
#include <hip/hip_runtime.h>
#include <hip/hip_bf16.h>
#include <math.h>

#define CH 64
#define HH 128
#define WW 128
#define HW 16384
#define NVALS 131072.f

// ws layout (float offsets):
//  STATS 0 (256 f: [128 unused] + ab[128]) | BIAS2 256 (108 f)
//  WACONV 384 (64512 ushort) | WADCN 32640 (147456 ushort)
//  OACC 106368 (3538944 ushort bf16, [b][m=g*27+j][px])
//  XT 1875840 (2097152 ushort bf16, [b][px][c])
//  PARTS 2924416 (262144 f: [128 stats][2048 blocks])   total 12.7 MB
#define STATS  0
#define BIAS2  256
#define WACONV 384
#define WADCN  32640
#define OACC   106368
#define XT     1875840
#define PARTS  2924416

typedef unsigned short ushort_t;
typedef unsigned int uint_t;
typedef __attribute__((ext_vector_type(8))) short bf16x8;
typedef __attribute__((ext_vector_type(4))) float f32x4;

__device__ __forceinline__ float bflo(uint_t u) { return __uint_as_float(u << 16); }
__device__ __forceinline__ float bfhi(uint_t u) { return __uint_as_float(u & 0xFFFF0000u); }
__device__ __forceinline__ float bfu(ushort_t s) { return __uint_as_float(((uint_t)s) << 16); }
__device__ __forceinline__ ushort_t f2bf(float f) {
    __hip_bfloat16 h = __float2bfloat16(f);
    return *(ushort_t*)&h;
}
__device__ __forceinline__ uint_t pack2(float lo, float hi) {
    return (uint_t)f2bf(lo) | ((uint_t)f2bf(hi) << 16);
}

__device__ __forceinline__ int off_chan(int g, int j) {
    return (j < 18) ? (g * 18 + j) : (72 + g * 9 + (j - 18));
}

__global__ void prep(const float* __restrict__ w_offset, const float* __restrict__ b_offset,
                     const float* __restrict__ w_dcn, float* __restrict__ ws) {
    int tid = blockIdx.x * 256 + threadIdx.x;
    if (tid < 64512) {   // conv MFMA A-frags: ((kt*7+mt)*64+lane)*8+jp
        int jp = tid & 7;
        int lane = (tid >> 3) & 63;
        int rest = tid >> 9;
        int mt = rest % 7;
        int kt = rest / 7;
        int m = mt * 16 + (lane & 15);
        int off = ((lane >> 4) << 3) + jp;
        int c = ((kt & 1) << 5) + off;
        int k = kt >> 1;
        float s = 0.f;
        if (m < 108) {
            int och = off_chan(m / 27, m % 27);
#pragma unroll
            for (int ss = 0; ss < 4; ++ss)
                s += w_offset[(och * 256 + ss * 64 + c) * 9 + k];
        }
        ((ushort_t*)(ws + WACONV))[tid] = f2bf(s);
    }
    if (tid < 147456) {  // dcn MFMA A-frags: (((g*18+kt)*4+mt)*64+lane)*8+jp
        int jp = tid & 7;
        int lane = (tid >> 3) & 63;
        int q = tid >> 9;
        int mt = q & 3;
        int kt = (q >> 2) % 18;
        int g = q / 72;
        int m = mt * 16 + (lane & 15);
        int c = ((kt & 1) << 5) + ((lane >> 4) << 3) + jp;
        int tap = kt >> 1;
        ((ushort_t*)(ws + WADCN))[tid] = f2bf(w_dcn[((g * 64 + m) * 64 + c) * 9 + tap]);
    }
    if (tid < 108) ws[BIAS2 + tid] = b_offset[off_chan(tid / 27, tid % 27)];
}

// x [b][c][px] f32 -> xT [b][px][c] bf16.  grid 512
__global__ __launch_bounds__(256) void transpose_x(const float* __restrict__ x,
                                                   ushort_t* __restrict__ xT) {
    int b = blockIdx.x >> 8;
    int px0 = (blockIdx.x & 255) << 6;
    __shared__ float lds[64][65];
    int t = threadIdx.x;
    int lx = t & 63;
    int row = t >> 6;
    const float* xb = x + (size_t)b * CH * HW;
#pragma unroll
    for (int i = 0; i < 16; ++i) {
        int c = i * 4 + row;
        lds[c][lx] = xb[(size_t)c * HW + px0 + lx];
    }
    __syncthreads();
    ushort_t* dst = xT + ((size_t)b * HW + px0) * 64;
#pragma unroll
    for (int i = 0; i < 16; ++i) {
        int p = i * 4 + row;
        dst[(size_t)p * 64 + lx] = f2bf(lds[lx][p]);
    }
}

// offset conv as MFMA implicit GEMM (r13 version: grid 256, 8-row tiles).
__global__ __launch_bounds__(256, 2) void conv_mfma(const ushort_t* __restrict__ xT,
                                                    const ushort_t* __restrict__ wA,
                                                    const float* __restrict__ biasM,
                                                    ushort_t* __restrict__ oaccb) {
    int blk = blockIdx.x;
    int b = blk >> 7;
    int tile = blk & 127;
    int th = tile >> 3, tw = tile & 7;
    int t = threadIdx.x;
    int wv = t >> 6, lane = t & 63;
    int lw = lane & 15, kg = lane >> 4;

    __shared__ ushort_t lds[180 * 72];

    const ushort_t* xTb = xT + (size_t)b * HW * 64;
    for (int rr = t; rr < 180; rr += 256) {
        int r = rr / 18, c2 = rr - r * 18;
        int hy = th * 8 + r - 1, wx = tw * 16 + c2 - 1;
        bool valid = (hy >= 0) && (hy < HH) && (wx >= 0) && (wx < WW);
        uint4* dst = (uint4*)&lds[rr * 72];
        if (valid) {
            const uint4* src = (const uint4*)(xTb + ((size_t)(hy * WW + wx)) * 64);
#pragma unroll
            for (int ch = 0; ch < 8; ++ch) dst[ch] = src[ch];
        } else {
            uint4 z; z.x = z.y = z.z = z.w = 0;
#pragma unroll
            for (int ch = 0; ch < 8; ++ch) dst[ch] = z;
        }
    }
    __syncthreads();

    f32x4 acc[7][2];
#pragma unroll
    for (int mt = 0; mt < 7; ++mt)
#pragma unroll
        for (int i = 0; i < 2; ++i)
            acc[mt][i] = (f32x4){0.f, 0.f, 0.f, 0.f};

    const bf16x8* wAv = (const bf16x8*)wA;
    for (int kt = 0; kt < 18; ++kt) {
        int k = kt >> 1;
        int dh = k / 3, dw = k - dh * 3;
        int hh = kt & 1;
        bf16x8 bfrag[2];
#pragma unroll
        for (int i = 0; i < 2; ++i) {
            int nt = wv * 2 + i;
            int rr = (nt + dh) * 18 + lw + dw;
            bfrag[i] = *(const bf16x8*)&lds[rr * 72 + ((hh << 2) + kg) * 8];
        }
        bf16x8 afrag[7];
#pragma unroll
        for (int mt = 0; mt < 7; ++mt)
            afrag[mt] = wAv[(kt * 7 + mt) * 64 + lane];
#pragma unroll
        for (int mt = 0; mt < 7; ++mt)
#pragma unroll
            for (int i = 0; i < 2; ++i)
                acc[mt][i] = __builtin_amdgcn_mfma_f32_16x16x32_bf16(
                    afrag[mt], bfrag[i], acc[mt][i], 0, 0, 0);
    }

#pragma unroll
    for (int mt = 0; mt < 7; ++mt) {
#pragma unroll
        for (int r = 0; r < 4; ++r) {
            int m = mt * 16 + (kg << 2) + r;
            if (m < 108) {
                float bia = biasM[m];
#pragma unroll
                for (int i = 0; i < 2; ++i) {
                    int hgl = th * 8 + wv * 2 + i;
                    int wgl = tw * 16 + lw;
                    oaccb[((size_t)b * 108 + m) * HW + hgl * WW + wgl] =
                        f2bf(acc[mt][i][r] + bia);
                }
            }
        }
    }
}

// deformable conv MFMA + fused stats.  grid 2048 (8 blocks/CU), 64 px/block.
// xcd = blk&7 -> (b = xcd>>2, quad = xcd&3); unit = blk>>3 (0..255):
// g = unit>>6, tl = unit&63 -> trow = tl>>3 (0..7), tcol = tl&7.
// tile = 4 rows x 16 cols at (quad*32 + trow*4, tcol*16).
// 4 waves: wave wv owns N-tile wv (16 px); 4 M-tiles; K 18.
__global__ __launch_bounds__(256, 8) void dcn_mfma(const ushort_t* __restrict__ xT,
                                                   const ushort_t* __restrict__ oaccb,
                                                   const ushort_t* __restrict__ wA,
                                                   float* __restrict__ out,
                                                   float* __restrict__ parts) {
    int blk = blockIdx.x;
    int xcd = blk & 7;
    int b = xcd >> 2;
    int quad = xcd & 3;
    int unit = blk >> 3;
    int g = unit >> 6;
    int tl = unit & 63;
    int trow = tl >> 3;
    int tcol = tl & 7;
    int t = threadIdx.x;
    int wv = t >> 6, lane = t & 63;
    int lw = lane & 15, kg = lane >> 4;

    __shared__ ushort_t colLDS[64 * 72];      // 9.2 KB
    __shared__ uint_t idxLDS[2][4][64];       // 2 KB (double-buffered)
    __shared__ float  wgtLDS[2][4][64];       // 2 KB
    __shared__ float  sumLDS[4][64];          // 1 KB
    __shared__ float  sqLDS[4][64];           // 1 KB

    const ushort_t* xTb = xT + (size_t)b * HW * 64;

    // phase-1 pixel for this thread (threads 0..63)
    int p1 = t & 63;
    int h1 = quad * 32 + trow * 4 + (p1 >> 4);
    int w1 = tcol * 16 + (p1 & 15);
    const ushort_t* ob_in = oaccb + (size_t)(b * 4 + g) * 27 * HW + h1 * WW + w1;

#define P1(KK, BUF)                                                               \
    if (t < 64) {                                                                 \
        float dy = bfu(ob_in[(size_t)(2 * (KK)) * HW]);                           \
        float dx = bfu(ob_in[(size_t)(2 * (KK) + 1) * HW]);                       \
        float mk = 1.f / (1.f + expf(-bfu(ob_in[(size_t)(18 + (KK)) * HW])));     \
        float py = (float)h1 + (float)((KK) / 3 - 1) + dy;                        \
        float qx = (float)w1 + (float)((KK) % 3 - 1) + dx;                        \
        float y0f = floorf(py), x0f = floorf(qx);                                 \
        float ly = py - y0f, lx = qx - x0f;                                       \
        int y0 = (int)y0f, x0 = (int)x0f;                                         \
        int y1 = y0 + 1, x1 = x0 + 1;                                             \
        bool vy0 = (y0 >= 0) && (y0 < HH), vy1 = (y1 >= 0) && (y1 < HH);          \
        bool vx0 = (x0 >= 0) && (x0 < WW), vx1 = (x1 >= 0) && (x1 < WW);          \
        int yc0 = min(max(y0, 0), HH - 1), yc1 = min(max(y1, 0), HH - 1);         \
        int xc0 = min(max(x0, 0), WW - 1), xc1 = min(max(x1, 0), WW - 1);         \
        idxLDS[BUF][0][p1] = (uint_t)(yc0 * WW + xc0);                            \
        idxLDS[BUF][1][p1] = (uint_t)(yc0 * WW + xc1);                            \
        idxLDS[BUF][2][p1] = (uint_t)(yc1 * WW + xc0);                            \
        idxLDS[BUF][3][p1] = (uint_t)(yc1 * WW + xc1);                            \
        wgtLDS[BUF][0][p1] = (1.f - ly) * (1.f - lx) * mk * ((vy0 && vx0) ? 1.f : 0.f); \
        wgtLDS[BUF][1][p1] = (1.f - ly) * lx * mk * ((vy0 && vx1) ? 1.f : 0.f);   \
        wgtLDS[BUF][2][p1] = ly * (1.f - lx) * mk * ((vy1 && vx0) ? 1.f : 0.f);   \
        wgtLDS[BUF][3][p1] = ly * lx * mk * ((vy1 && vx1) ? 1.f : 0.f);           \
    }

    f32x4 acc[4];
#pragma unroll
    for (int mt = 0; mt < 4; ++mt)
        acc[mt] = (f32x4){0.f, 0.f, 0.f, 0.f};

    const bf16x8* wAv = (const bf16x8*)wA + (size_t)g * 4608;

    P1(0, 0);
    __syncthreads();

    for (int k = 0; k < 9; ++k) {
        int cur = k & 1;
        // ---- phase 2: grouped gathers (8 lanes share one pixel row) ----
        int chunk = t & 7;
#pragma unroll
        for (int iter = 0; iter < 2; ++iter) {
            int p = iter * 32 + (t >> 3);
            uint_t i00 = idxLDS[cur][0][p], i01 = idxLDS[cur][1][p];
            uint_t i10 = idxLDS[cur][2][p], i11 = idxLDS[cur][3][p];
            float w00 = wgtLDS[cur][0][p], w01 = wgtLDS[cur][1][p];
            float w10 = wgtLDS[cur][2][p], w11 = wgtLDS[cur][3][p];
            uint4 u00 = *(const uint4*)(xTb + (size_t)i00 * 64 + chunk * 8);
            uint4 u01 = *(const uint4*)(xTb + (size_t)i01 * 64 + chunk * 8);
            uint4 u10 = *(const uint4*)(xTb + (size_t)i10 * 64 + chunk * 8);
            uint4 u11 = *(const uint4*)(xTb + (size_t)i11 * 64 + chunk * 8);
            uint4 res;
#define CMB(E) pack2(w00 * bflo(u00.E) + w01 * bflo(u01.E) + w10 * bflo(u10.E) + w11 * bflo(u11.E), \
                     w00 * bfhi(u00.E) + w01 * bfhi(u01.E) + w10 * bfhi(u10.E) + w11 * bfhi(u11.E))
            res.x = CMB(x);
            res.y = CMB(y);
            res.z = CMB(z);
            res.w = CMB(w);
#undef CMB
            *(uint4*)&colLDS[p * 72 + chunk * 8] = res;
        }
        __syncthreads();

        // ---- phase 1 for next tap (VALU) overlapped with MFMA (matrix pipe) ----
        if (k < 8) { P1(k + 1, cur ^ 1); }

        // ---- MFMA phase ----
#pragma unroll
        for (int kt2 = 0; kt2 < 2; ++kt2) {
            int kt = k * 2 + kt2;
            bf16x8 bfrag = *(const bf16x8*)
                &colLDS[(wv * 16 + lw) * 72 + (kt2 * 4 + kg) * 8];
            bf16x8 afrag[4];
#pragma unroll
            for (int mt = 0; mt < 4; ++mt)
                afrag[mt] = wAv[(kt * 4 + mt) * 64 + lane];
#pragma unroll
            for (int mt = 0; mt < 4; ++mt)
                acc[mt] = __builtin_amdgcn_mfma_f32_16x16x32_bf16(
                    afrag[mt], bfrag, acc[mt], 0, 0, 0);
        }
        __syncthreads();
    }
#undef P1

    // ---- epilogue: pixel-shuffle store + fused per-block stats partials ----
    int s1 = g >> 1, s2g = g & 1;
    int hg = quad * 32 + trow * 4 + wv;
    int wg = tcol * 16 + lw;
#pragma unroll
    for (int mt = 0; mt < 4; ++mt) {
        float* op = out + ((size_t)b * 64 + mt * 16 + (kg << 2)) * 65536
                  + (size_t)(hg * 2 + s1) * 256 + (wg * 2 + s2g);
#pragma unroll
        for (int r = 0; r < 4; ++r)
            op[(size_t)r * 65536] = acc[mt][r];
    }

    // per-wave channel partials: reduce over the 16 lw lanes (same channel)
#pragma unroll
    for (int mt = 0; mt < 4; ++mt) {
#pragma unroll
        for (int r = 0; r < 4; ++r) {
            float a0 = acc[mt][r];
            float s = a0;
            float s2 = a0 * a0;
#pragma unroll
            for (int m = 1; m < 16; m <<= 1) {
                s += __shfl_xor(s, m);
                s2 += __shfl_xor(s2, m);
            }
            if (lw == 0) {
                int ml = mt * 16 + (kg << 2) + r;
                sumLDS[wv][ml] = s;
                sqLDS[wv][ml] = s2;
            }
        }
    }
    __syncthreads();
    if (t < 128) {
        int o = t & 63;
        bool isq = t >= 64;
        float v = 0.f;
#pragma unroll
        for (int w2 = 0; w2 < 4; ++w2)
            v += isq ? sqLDS[w2][o] : sumLDS[w2][o];
        parts[(size_t)(isq ? 64 + o : o) * 2048 + blk] = v;
    }
}

// reduce 2048 per-block partials -> a/b per channel.  grid 64.
__global__ __launch_bounds__(256) void stats_reduce(const float* __restrict__ parts,
                                                    const float* __restrict__ gamma,
                                                    const float* __restrict__ beta,
                                                    float* __restrict__ ab) {
    int o = blockIdx.x;
    int t = threadIdx.x;
    float s = 0.f, s2 = 0.f;
    for (int i = t; i < 2048; i += 256) {
        s += parts[(size_t)o * 2048 + i];
        s2 += parts[(size_t)(64 + o) * 2048 + i];
    }
    __shared__ float red[512];
    red[t] = s;
    red[256 + t] = s2;
    __syncthreads();
#pragma unroll
    for (int m = 128; m >= 1; m >>= 1) {
        if (t < m) {
            red[t] += red[t + m];
            red[256 + t] += red[256 + t + m];
        }
        __syncthreads();
    }
    if (t == 0) {
        float mean = red[0] / NVALS;
        float var = red[256] / NVALS - mean * mean;
        var = fmaxf(var, 0.f);
        float a = gamma[o] * rsqrtf(var + 1e-5f);
        ab[o] = a;
        ab[64 + o] = beta[o] - mean * a;
    }
}

__global__ void norm_relu(float* __restrict__ out, const float* __restrict__ ab) {
    size_t tid = (size_t)blockIdx.x * 256 + threadIdx.x;
    size_t base = tid * 4;
    int o = (int)((base >> 16) & 63);
    float a = ab[o], bb = ab[64 + o];
    float4* p = (float4*)(out + base);
    float4 v = *p;
    v.x = fmaxf(fmaf(v.x, a, bb), 0.f);
    v.y = fmaxf(fmaf(v.y, a, bb), 0.f);
    v.z = fmaxf(fmaf(v.z, a, bb), 0.f);
    v.w = fmaxf(fmaf(v.w, a, bb), 0.f);
    *p = v;
}

extern "C" void kernel_launch(void* const* d_in, const int* in_sizes, int n_in,
                              void* d_out, int out_size, void* d_ws, size_t ws_size,
                              hipStream_t stream) {
    const float* x        = (const float*)d_in[0];
    const float* w_offset = (const float*)d_in[1];
    const float* b_offset = (const float*)d_in[2];
    const float* w_dcn    = (const float*)d_in[3];
    const float* gamma    = (const float*)d_in[4];
    const float* beta     = (const float*)d_in[5];
    float* out            = (float*)d_out;
    float* ws = (float*)d_ws;

    prep<<<576, 256, 0, stream>>>(w_offset, b_offset, w_dcn, ws);
    transpose_x<<<512, 256, 0, stream>>>(x, (ushort_t*)(ws + XT));
    conv_mfma<<<256, 256, 0, stream>>>((ushort_t*)(ws + XT), (ushort_t*)(ws + WACONV),
                                       ws + BIAS2, (ushort_t*)(ws + OACC));
    dcn_mfma<<<2048, 256, 0, stream>>>((ushort_t*)(ws + XT), (ushort_t*)(ws + OACC),
                                       (ushort_t*)(ws + WADCN), out, ws + PARTS);
    stats_reduce<<<64, 256, 0, stream>>>(ws + PARTS, gamma, beta, ws + STATS + 128);
    norm_relu<<<8192, 256, 0, stream>>>(out, ws + STATS + 128);
}

// Round 19
// 96.030 us; speedup vs baseline: 1.1500x; 1.1500x over previous
//
#include <hip/hip_runtime.h>
#include <hip/hip_bf16.h>
#include <math.h>

#define CH 64
#define HH 128
#define WW 128
#define HW 16384
#define NVALS 131072.f

// ws layout (float offsets):
//  STATS 0 (256 f: [128 unused] + ab[128] at STATS+128) | BIAS2 256 (108 f)
//  WACONV 384 (64512 ushort) | WADCN 32640 (147456 ushort)
//  OACC 106368 (3538944 ushort bf16, [b][m=g*27+j][px])
//  XT 1875840 (2097152 ushort bf16, [b][px][c])
//  PARTS 2924416 (131072 f: [128 stats][1024 blocks])   total ~12.2 MB
#define STATS  0
#define BIAS2  256
#define WACONV 384
#define WADCN  32640
#define OACC   106368
#define XT     1875840
#define PARTS  2924416

typedef unsigned short ushort_t;
typedef unsigned int uint_t;
typedef __attribute__((ext_vector_type(8))) short bf16x8;
typedef __attribute__((ext_vector_type(4))) float f32x4;

__device__ __forceinline__ float bflo(uint_t u) { return __uint_as_float(u << 16); }
__device__ __forceinline__ float bfhi(uint_t u) { return __uint_as_float(u & 0xFFFF0000u); }
__device__ __forceinline__ float bfu(ushort_t s) { return __uint_as_float(((uint_t)s) << 16); }
__device__ __forceinline__ ushort_t f2bf(float f) {
    __hip_bfloat16 h = __float2bfloat16(f);
    return *(ushort_t*)&h;
}
__device__ __forceinline__ uint_t pack2(float lo, float hi) {
    return (uint_t)f2bf(lo) | ((uint_t)f2bf(hi) << 16);
}

__device__ __forceinline__ int off_chan(int g, int j) {
    return (j < 18) ? (g * 18 + j) : (72 + g * 9 + (j - 18));
}

__global__ void prep(const float* __restrict__ w_offset, const float* __restrict__ b_offset,
                     const float* __restrict__ w_dcn, float* __restrict__ ws) {
    int tid = blockIdx.x * 256 + threadIdx.x;
    if (tid < 64512) {   // conv MFMA A-frags: ((kt*7+mt)*64+lane)*8+jp
        int jp = tid & 7;
        int lane = (tid >> 3) & 63;
        int rest = tid >> 9;
        int mt = rest % 7;
        int kt = rest / 7;
        int m = mt * 16 + (lane & 15);
        int off = ((lane >> 4) << 3) + jp;
        int c = ((kt & 1) << 5) + off;
        int k = kt >> 1;
        float s = 0.f;
        if (m < 108) {
            int och = off_chan(m / 27, m % 27);
#pragma unroll
            for (int ss = 0; ss < 4; ++ss)
                s += w_offset[(och * 256 + ss * 64 + c) * 9 + k];
        }
        ((ushort_t*)(ws + WACONV))[tid] = f2bf(s);
    }
    if (tid < 147456) {  // dcn MFMA A-frags: (((g*18+kt)*4+mt)*64+lane)*8+jp
        int jp = tid & 7;
        int lane = (tid >> 3) & 63;
        int q = tid >> 9;
        int mt = q & 3;
        int kt = (q >> 2) % 18;
        int g = q / 72;
        int m = mt * 16 + (lane & 15);
        int c = ((kt & 1) << 5) + ((lane >> 4) << 3) + jp;
        int tap = kt >> 1;
        ((ushort_t*)(ws + WADCN))[tid] = f2bf(w_dcn[((g * 64 + m) * 64 + c) * 9 + tap]);
    }
    if (tid < 108) ws[BIAS2 + tid] = b_offset[off_chan(tid / 27, tid % 27)];
}

// x [b][c][px] f32 -> xT [b][px][c] bf16.  grid 512
__global__ __launch_bounds__(256) void transpose_x(const float* __restrict__ x,
                                                   ushort_t* __restrict__ xT) {
    int b = blockIdx.x >> 8;
    int px0 = (blockIdx.x & 255) << 6;
    __shared__ float lds[64][65];
    int t = threadIdx.x;
    int lx = t & 63;
    int row = t >> 6;
    const float* xb = x + (size_t)b * CH * HW;
#pragma unroll
    for (int i = 0; i < 16; ++i) {
        int c = i * 4 + row;
        lds[c][lx] = xb[(size_t)c * HW + px0 + lx];
    }
    __syncthreads();
    ushort_t* dst = xT + ((size_t)b * HW + px0) * 64;
#pragma unroll
    for (int i = 0; i < 16; ++i) {
        int p = i * 4 + row;
        dst[(size_t)p * 64 + lx] = f2bf(lds[lx][p]);
    }
}

// offset conv as MFMA implicit GEMM (r13 version: grid 256, 8-row tiles).
__global__ __launch_bounds__(256, 2) void conv_mfma(const ushort_t* __restrict__ xT,
                                                    const ushort_t* __restrict__ wA,
                                                    const float* __restrict__ biasM,
                                                    ushort_t* __restrict__ oaccb) {
    int blk = blockIdx.x;
    int b = blk >> 7;
    int tile = blk & 127;
    int th = tile >> 3, tw = tile & 7;
    int t = threadIdx.x;
    int wv = t >> 6, lane = t & 63;
    int lw = lane & 15, kg = lane >> 4;

    __shared__ ushort_t lds[180 * 72];

    const ushort_t* xTb = xT + (size_t)b * HW * 64;
    for (int rr = t; rr < 180; rr += 256) {
        int r = rr / 18, c2 = rr - r * 18;
        int hy = th * 8 + r - 1, wx = tw * 16 + c2 - 1;
        bool valid = (hy >= 0) && (hy < HH) && (wx >= 0) && (wx < WW);
        uint4* dst = (uint4*)&lds[rr * 72];
        if (valid) {
            const uint4* src = (const uint4*)(xTb + ((size_t)(hy * WW + wx)) * 64);
#pragma unroll
            for (int ch = 0; ch < 8; ++ch) dst[ch] = src[ch];
        } else {
            uint4 z; z.x = z.y = z.z = z.w = 0;
#pragma unroll
            for (int ch = 0; ch < 8; ++ch) dst[ch] = z;
        }
    }
    __syncthreads();

    f32x4 acc[7][2];
#pragma unroll
    for (int mt = 0; mt < 7; ++mt)
#pragma unroll
        for (int i = 0; i < 2; ++i)
            acc[mt][i] = (f32x4){0.f, 0.f, 0.f, 0.f};

    const bf16x8* wAv = (const bf16x8*)wA;
    for (int kt = 0; kt < 18; ++kt) {
        int k = kt >> 1;
        int dh = k / 3, dw = k - dh * 3;
        int hh = kt & 1;
        bf16x8 bfrag[2];
#pragma unroll
        for (int i = 0; i < 2; ++i) {
            int nt = wv * 2 + i;
            int rr = (nt + dh) * 18 + lw + dw;
            bfrag[i] = *(const bf16x8*)&lds[rr * 72 + ((hh << 2) + kg) * 8];
        }
        bf16x8 afrag[7];
#pragma unroll
        for (int mt = 0; mt < 7; ++mt)
            afrag[mt] = wAv[(kt * 7 + mt) * 64 + lane];
#pragma unroll
        for (int mt = 0; mt < 7; ++mt)
#pragma unroll
            for (int i = 0; i < 2; ++i)
                acc[mt][i] = __builtin_amdgcn_mfma_f32_16x16x32_bf16(
                    afrag[mt], bfrag[i], acc[mt][i], 0, 0, 0);
    }

#pragma unroll
    for (int mt = 0; mt < 7; ++mt) {
#pragma unroll
        for (int r = 0; r < 4; ++r) {
            int m = mt * 16 + (kg << 2) + r;
            if (m < 108) {
                float bia = biasM[m];
#pragma unroll
                for (int i = 0; i < 2; ++i) {
                    int hgl = th * 8 + wv * 2 + i;
                    int wgl = tw * 16 + lw;
                    oaccb[((size_t)b * 108 + m) * HW + hgl * WW + wgl] =
                        f2bf(acc[mt][i][r] + bia);
                }
            }
        }
    }
}

// deformable conv MFMA + fused stats partials.  grid 1024 (4 blocks/CU).
// Per tap: phase2 (grouped gathers) -> barrier -> [phase1(k+1) overlapped with MFMA(k)]
// -> barrier.  idx/wgt double-buffered.  Epilogue: per-block per-channel partial
// sum/sumsq via shuffle + LDS (NO atomics), written to parts[128][1024].
__global__ __launch_bounds__(256, 4) void dcn_mfma(const ushort_t* __restrict__ xT,
                                                   const ushort_t* __restrict__ oaccb,
                                                   const ushort_t* __restrict__ wA,
                                                   float* __restrict__ out,
                                                   float* __restrict__ parts) {
    int blk = blockIdx.x;
    int xcd = blk & 7;
    int b = xcd >> 2;
    int quad = xcd & 3;
    int unit = blk >> 3;
    int g = unit >> 5;
    int tl = unit & 31;
    int th = quad * 4 + (tl >> 3);
    int tw = tl & 7;
    int t = threadIdx.x;
    int wv = t >> 6, lane = t & 63;
    int lw = lane & 15, kg = lane >> 4;

    __shared__ ushort_t colLDS[128 * 72];     // 18.4 KB
    __shared__ uint_t idxLDS[2][4][128];      // 4 KB (double-buffered)
    __shared__ float  wgtLDS[2][4][128];      // 4 KB
    __shared__ float  sumLDS[4][64];          // 1 KB
    __shared__ float  sqLDS[4][64];           // 1 KB

    const ushort_t* xTb = xT + (size_t)b * HW * 64;

    // phase-1 pixel for this thread (threads 0..127)
    int p1 = t & 127;
    int h1 = th * 8 + (p1 >> 4);
    int w1 = tw * 16 + (p1 & 15);
    const ushort_t* ob_in = oaccb + (size_t)(b * 4 + g) * 27 * HW + h1 * WW + w1;

#define P1(KK, BUF)                                                               \
    if (t < 128) {                                                                \
        float dy = bfu(ob_in[(size_t)(2 * (KK)) * HW]);                           \
        float dx = bfu(ob_in[(size_t)(2 * (KK) + 1) * HW]);                       \
        float mk = 1.f / (1.f + expf(-bfu(ob_in[(size_t)(18 + (KK)) * HW])));     \
        float py = (float)h1 + (float)((KK) / 3 - 1) + dy;                        \
        float qx = (float)w1 + (float)((KK) % 3 - 1) + dx;                        \
        float y0f = floorf(py), x0f = floorf(qx);                                 \
        float ly = py - y0f, lx = qx - x0f;                                       \
        int y0 = (int)y0f, x0 = (int)x0f;                                         \
        int y1 = y0 + 1, x1 = x0 + 1;                                             \
        bool vy0 = (y0 >= 0) && (y0 < HH), vy1 = (y1 >= 0) && (y1 < HH);          \
        bool vx0 = (x0 >= 0) && (x0 < WW), vx1 = (x1 >= 0) && (x1 < WW);          \
        int yc0 = min(max(y0, 0), HH - 1), yc1 = min(max(y1, 0), HH - 1);         \
        int xc0 = min(max(x0, 0), WW - 1), xc1 = min(max(x1, 0), WW - 1);         \
        idxLDS[BUF][0][p1] = (uint_t)(yc0 * WW + xc0);                            \
        idxLDS[BUF][1][p1] = (uint_t)(yc0 * WW + xc1);                            \
        idxLDS[BUF][2][p1] = (uint_t)(yc1 * WW + xc0);                            \
        idxLDS[BUF][3][p1] = (uint_t)(yc1 * WW + xc1);                            \
        wgtLDS[BUF][0][p1] = (1.f - ly) * (1.f - lx) * mk * ((vy0 && vx0) ? 1.f : 0.f); \
        wgtLDS[BUF][1][p1] = (1.f - ly) * lx * mk * ((vy0 && vx1) ? 1.f : 0.f);   \
        wgtLDS[BUF][2][p1] = ly * (1.f - lx) * mk * ((vy1 && vx0) ? 1.f : 0.f);   \
        wgtLDS[BUF][3][p1] = ly * lx * mk * ((vy1 && vx1) ? 1.f : 0.f);           \
    }

    f32x4 acc[4][2];
#pragma unroll
    for (int mt = 0; mt < 4; ++mt)
#pragma unroll
        for (int i = 0; i < 2; ++i)
            acc[mt][i] = (f32x4){0.f, 0.f, 0.f, 0.f};

    const bf16x8* wAv = (const bf16x8*)wA + (size_t)g * 4608;

    P1(0, 0);
    __syncthreads();

    for (int k = 0; k < 9; ++k) {
        int cur = k & 1;
        // ---- phase 2: grouped gathers (8 lanes share one pixel row) ----
        int chunk = t & 7;
#pragma unroll
        for (int iter = 0; iter < 4; ++iter) {
            int p = iter * 32 + (t >> 3);
            uint_t i00 = idxLDS[cur][0][p], i01 = idxLDS[cur][1][p];
            uint_t i10 = idxLDS[cur][2][p], i11 = idxLDS[cur][3][p];
            float w00 = wgtLDS[cur][0][p], w01 = wgtLDS[cur][1][p];
            float w10 = wgtLDS[cur][2][p], w11 = wgtLDS[cur][3][p];
            uint4 u00 = *(const uint4*)(xTb + (size_t)i00 * 64 + chunk * 8);
            uint4 u01 = *(const uint4*)(xTb + (size_t)i01 * 64 + chunk * 8);
            uint4 u10 = *(const uint4*)(xTb + (size_t)i10 * 64 + chunk * 8);
            uint4 u11 = *(const uint4*)(xTb + (size_t)i11 * 64 + chunk * 8);
            uint4 res;
#define CMB(E) pack2(w00 * bflo(u00.E) + w01 * bflo(u01.E) + w10 * bflo(u10.E) + w11 * bflo(u11.E), \
                     w00 * bfhi(u00.E) + w01 * bfhi(u01.E) + w10 * bfhi(u10.E) + w11 * bfhi(u11.E))
            res.x = CMB(x);
            res.y = CMB(y);
            res.z = CMB(z);
            res.w = CMB(w);
#undef CMB
            *(uint4*)&colLDS[p * 72 + chunk * 8] = res;
        }
        __syncthreads();

        // ---- phase 1 for next tap (VALU) overlapped with MFMA (matrix pipe) ----
        if (k < 8) { P1(k + 1, cur ^ 1); }

        // ---- MFMA phase ----
#pragma unroll
        for (int kt2 = 0; kt2 < 2; ++kt2) {
            int kt = k * 2 + kt2;
            bf16x8 bfrag[2];
#pragma unroll
            for (int i = 0; i < 2; ++i)
                bfrag[i] = *(const bf16x8*)
                    &colLDS[((wv * 2 + i) * 16 + lw) * 72 + (kt2 * 4 + kg) * 8];
            bf16x8 afrag[4];
#pragma unroll
            for (int mt = 0; mt < 4; ++mt)
                afrag[mt] = wAv[(kt * 4 + mt) * 64 + lane];
#pragma unroll
            for (int mt = 0; mt < 4; ++mt)
#pragma unroll
                for (int i = 0; i < 2; ++i)
                    acc[mt][i] = __builtin_amdgcn_mfma_f32_16x16x32_bf16(
                        afrag[mt], bfrag[i], acc[mt][i], 0, 0, 0);
        }
        __syncthreads();
    }
#undef P1

    // ---- epilogue: pixel-shuffle store + fused per-block stats partials ----
    int s1 = g >> 1, s2g = g & 1;
#pragma unroll
    for (int mt = 0; mt < 4; ++mt) {
#pragma unroll
        for (int i = 0; i < 2; ++i) {
            int p2 = (wv * 2 + i) * 16 + lw;
            int hg = th * 8 + (p2 >> 4);
            int wg = tw * 16 + (p2 & 15);
            float* op = out + ((size_t)b * 64 + mt * 16 + (kg << 2)) * 65536
                      + (size_t)(hg * 2 + s1) * 256 + (wg * 2 + s2g);
#pragma unroll
            for (int r = 0; r < 4; ++r)
                op[(size_t)r * 65536] = acc[mt][i][r];
        }
    }

    // per-wave channel partials: reduce over the 16 lw lanes (same channel)
#pragma unroll
    for (int mt = 0; mt < 4; ++mt) {
#pragma unroll
        for (int r = 0; r < 4; ++r) {
            float a0 = acc[mt][0][r], a1 = acc[mt][1][r];
            float s = a0 + a1;
            float s2 = a0 * a0 + a1 * a1;
#pragma unroll
            for (int m = 1; m < 16; m <<= 1) {
                s += __shfl_xor(s, m);
                s2 += __shfl_xor(s2, m);
            }
            if (lw == 0) {
                int ml = mt * 16 + (kg << 2) + r;
                sumLDS[wv][ml] = s;
                sqLDS[wv][ml] = s2;
            }
        }
    }
    __syncthreads();
    if (t < 128) {
        int o = t & 63;
        bool isq = t >= 64;
        float v = 0.f;
#pragma unroll
        for (int w2 = 0; w2 < 4; ++w2)
            v += isq ? sqLDS[w2][o] : sumLDS[w2][o];
        parts[(size_t)(isq ? 64 + o : o) * 1024 + blk] = v;
    }
}

// reduce 1024 per-block partials -> a/b per channel.  grid 64.
__global__ __launch_bounds__(256) void stats_reduce(const float* __restrict__ parts,
                                                    const float* __restrict__ gamma,
                                                    const float* __restrict__ beta,
                                                    float* __restrict__ ab) {
    int o = blockIdx.x;
    int t = threadIdx.x;
    float s = 0.f, s2 = 0.f;
    for (int i = t; i < 1024; i += 256) {
        s += parts[(size_t)o * 1024 + i];
        s2 += parts[(size_t)(64 + o) * 1024 + i];
    }
    __shared__ float red[512];
    red[t] = s;
    red[256 + t] = s2;
    __syncthreads();
#pragma unroll
    for (int m = 128; m >= 1; m >>= 1) {
        if (t < m) {
            red[t] += red[t + m];
            red[256 + t] += red[256 + t + m];
        }
        __syncthreads();
    }
    if (t == 0) {
        float mean = red[0] / NVALS;
        float var = red[256] / NVALS - mean * mean;
        var = fmaxf(var, 0.f);
        float a = gamma[o] * rsqrtf(var + 1e-5f);
        ab[o] = a;
        ab[64 + o] = beta[o] - mean * a;
    }
}

__global__ void norm_relu(float* __restrict__ out, const float* __restrict__ ab) {
    size_t tid = (size_t)blockIdx.x * 256 + threadIdx.x;
    size_t base = tid * 4;
    int o = (int)((base >> 16) & 63);
    float a = ab[o], bb = ab[64 + o];
    float4* p = (float4*)(out + base);
    float4 v = *p;
    v.x = fmaxf(fmaf(v.x, a, bb), 0.f);
    v.y = fmaxf(fmaf(v.y, a, bb), 0.f);
    v.z = fmaxf(fmaf(v.z, a, bb), 0.f);
    v.w = fmaxf(fmaf(v.w, a, bb), 0.f);
    *p = v;
}

extern "C" void kernel_launch(void* const* d_in, const int* in_sizes, int n_in,
                              void* d_out, int out_size, void* d_ws, size_t ws_size,
                              hipStream_t stream) {
    const float* x        = (const float*)d_in[0];
    const float* w_offset = (const float*)d_in[1];
    const float* b_offset = (const float*)d_in[2];
    const float* w_dcn    = (const float*)d_in[3];
    const float* gamma    = (const float*)d_in[4];
    const float* beta     = (const float*)d_in[5];
    float* out            = (float*)d_out;
    float* ws = (float*)d_ws;

    prep<<<576, 256, 0, stream>>>(w_offset, b_offset, w_dcn, ws);
    transpose_x<<<512, 256, 0, stream>>>(x, (ushort_t*)(ws + XT));
    conv_mfma<<<256, 256, 0, stream>>>((ushort_t*)(ws + XT), (ushort_t*)(ws + WACONV),
                                       ws + BIAS2, (ushort_t*)(ws + OACC));
    dcn_mfma<<<1024, 256, 0, stream>>>((ushort_t*)(ws + XT), (ushort_t*)(ws + OACC),
                                       (ushort_t*)(ws + WADCN), out, ws + PARTS);
    stats_reduce<<<64, 256, 0, stream>>>(ws + PARTS, gamma, beta, ws + STATS + 128);
    norm_relu<<<8192, 256, 0, stream>>>(out, ws + STATS + 128);
}

// Round 20
// 95.265 us; speedup vs baseline: 1.1592x; 1.0080x over previous
//
#include <hip/hip_runtime.h>
#include <hip/hip_bf16.h>
#include <math.h>

#define CH 64
#define HH 128
#define WW 128
#define HW 16384
#define NVALS 131072.f

// ws layout (float offsets):
//  STATS 0 (256 f: [128 unused] + ab[128] at STATS+128) | BIAS2 256 (108 f)
//  WACONV 384 (64512 ushort) | WADCN 32640 (147456 ushort)
//  OACC 106368 (3538944 ushort bf16, [b][m=g*27+j][px])
//  XT 1875840 (2097152 ushort bf16, [b][px][c])
//  PARTS 2924416 (131072 f: [128 stats][1024 blocks])   total ~12.2 MB
#define STATS  0
#define BIAS2  256
#define WACONV 384
#define WADCN  32640
#define OACC   106368
#define XT     1875840
#define PARTS  2924416

typedef unsigned short ushort_t;
typedef unsigned int uint_t;
typedef __attribute__((ext_vector_type(8))) short bf16x8;
typedef __attribute__((ext_vector_type(4))) float f32x4;

__device__ __forceinline__ float bflo(uint_t u) { return __uint_as_float(u << 16); }
__device__ __forceinline__ float bfhi(uint_t u) { return __uint_as_float(u & 0xFFFF0000u); }
__device__ __forceinline__ float bfu(ushort_t s) { return __uint_as_float(((uint_t)s) << 16); }
__device__ __forceinline__ ushort_t f2bf(float f) {
    __hip_bfloat16 h = __float2bfloat16(f);
    return *(ushort_t*)&h;
}
__device__ __forceinline__ uint_t pack2(float lo, float hi) {
    return (uint_t)f2bf(lo) | ((uint_t)f2bf(hi) << 16);
}

__device__ __forceinline__ int off_chan(int g, int j) {
    return (j < 18) ? (g * 18 + j) : (72 + g * 9 + (j - 18));
}

// merged prep (weight fragments) + x transpose.  grid 1088:
//  blocks 0..511   -> transpose_x part (b = blk>>8, px tile = blk&255)
//  blocks 512..1087 -> weight prep part (tid = (blk-512)*256+t)
__global__ __launch_bounds__(256) void prep_all(const float* __restrict__ x,
                                                const float* __restrict__ w_offset,
                                                const float* __restrict__ b_offset,
                                                const float* __restrict__ w_dcn,
                                                float* __restrict__ ws) {
    int blk = blockIdx.x;
    int t = threadIdx.x;
    if (blk < 512) {
        // ---- x [b][c][px] f32 -> xT [b][px][c] bf16 ----
        ushort_t* xT = (ushort_t*)(ws + XT);
        int b = blk >> 8;
        int px0 = (blk & 255) << 6;
        __shared__ float lds[64][65];
        int lx = t & 63;
        int row = t >> 6;
        const float* xb = x + (size_t)b * CH * HW;
#pragma unroll
        for (int i = 0; i < 16; ++i) {
            int c = i * 4 + row;
            lds[c][lx] = xb[(size_t)c * HW + px0 + lx];
        }
        __syncthreads();
        ushort_t* dst = xT + ((size_t)b * HW + px0) * 64;
#pragma unroll
        for (int i = 0; i < 16; ++i) {
            int p = i * 4 + row;
            dst[(size_t)p * 64 + lx] = f2bf(lds[lx][p]);
        }
        return;
    }
    int tid = (blk - 512) * 256 + t;
    if (tid < 64512) {   // conv MFMA A-frags: ((kt*7+mt)*64+lane)*8+jp
        int jp = tid & 7;
        int lane = (tid >> 3) & 63;
        int rest = tid >> 9;
        int mt = rest % 7;
        int kt = rest / 7;
        int m = mt * 16 + (lane & 15);
        int off = ((lane >> 4) << 3) + jp;
        int c = ((kt & 1) << 5) + off;
        int k = kt >> 1;
        float s = 0.f;
        if (m < 108) {
            int och = off_chan(m / 27, m % 27);
#pragma unroll
            for (int ss = 0; ss < 4; ++ss)
                s += w_offset[(och * 256 + ss * 64 + c) * 9 + k];
        }
        ((ushort_t*)(ws + WACONV))[tid] = f2bf(s);
    }
    if (tid < 147456) {  // dcn MFMA A-frags: (((g*18+kt)*4+mt)*64+lane)*8+jp
        int jp = tid & 7;
        int lane = (tid >> 3) & 63;
        int q = tid >> 9;
        int mt = q & 3;
        int kt = (q >> 2) % 18;
        int g = q / 72;
        int m = mt * 16 + (lane & 15);
        int c = ((kt & 1) << 5) + ((lane >> 4) << 3) + jp;
        int tap = kt >> 1;
        ((ushort_t*)(ws + WADCN))[tid] = f2bf(w_dcn[((g * 64 + m) * 64 + c) * 9 + tap]);
    }
    if (tid < 108) ws[BIAS2 + tid] = b_offset[off_chan(tid / 27, tid % 27)];
}

// offset conv as MFMA implicit GEMM (r13 version: grid 256, 8-row tiles).
__global__ __launch_bounds__(256, 2) void conv_mfma(const ushort_t* __restrict__ xT,
                                                    const ushort_t* __restrict__ wA,
                                                    const float* __restrict__ biasM,
                                                    ushort_t* __restrict__ oaccb) {
    int blk = blockIdx.x;
    int b = blk >> 7;
    int tile = blk & 127;
    int th = tile >> 3, tw = tile & 7;
    int t = threadIdx.x;
    int wv = t >> 6, lane = t & 63;
    int lw = lane & 15, kg = lane >> 4;

    __shared__ ushort_t lds[180 * 72];

    const ushort_t* xTb = xT + (size_t)b * HW * 64;
    for (int rr = t; rr < 180; rr += 256) {
        int r = rr / 18, c2 = rr - r * 18;
        int hy = th * 8 + r - 1, wx = tw * 16 + c2 - 1;
        bool valid = (hy >= 0) && (hy < HH) && (wx >= 0) && (wx < WW);
        uint4* dst = (uint4*)&lds[rr * 72];
        if (valid) {
            const uint4* src = (const uint4*)(xTb + ((size_t)(hy * WW + wx)) * 64);
#pragma unroll
            for (int ch = 0; ch < 8; ++ch) dst[ch] = src[ch];
        } else {
            uint4 z; z.x = z.y = z.z = z.w = 0;
#pragma unroll
            for (int ch = 0; ch < 8; ++ch) dst[ch] = z;
        }
    }
    __syncthreads();

    f32x4 acc[7][2];
#pragma unroll
    for (int mt = 0; mt < 7; ++mt)
#pragma unroll
        for (int i = 0; i < 2; ++i)
            acc[mt][i] = (f32x4){0.f, 0.f, 0.f, 0.f};

    const bf16x8* wAv = (const bf16x8*)wA;
    for (int kt = 0; kt < 18; ++kt) {
        int k = kt >> 1;
        int dh = k / 3, dw = k - dh * 3;
        int hh = kt & 1;
        bf16x8 bfrag[2];
#pragma unroll
        for (int i = 0; i < 2; ++i) {
            int nt = wv * 2 + i;
            int rr = (nt + dh) * 18 + lw + dw;
            bfrag[i] = *(const bf16x8*)&lds[rr * 72 + ((hh << 2) + kg) * 8];
        }
        bf16x8 afrag[7];
#pragma unroll
        for (int mt = 0; mt < 7; ++mt)
            afrag[mt] = wAv[(kt * 7 + mt) * 64 + lane];
#pragma unroll
        for (int mt = 0; mt < 7; ++mt)
#pragma unroll
            for (int i = 0; i < 2; ++i)
                acc[mt][i] = __builtin_amdgcn_mfma_f32_16x16x32_bf16(
                    afrag[mt], bfrag[i], acc[mt][i], 0, 0, 0);
    }

#pragma unroll
    for (int mt = 0; mt < 7; ++mt) {
#pragma unroll
        for (int r = 0; r < 4; ++r) {
            int m = mt * 16 + (kg << 2) + r;
            if (m < 108) {
                float bia = biasM[m];
#pragma unroll
                for (int i = 0; i < 2; ++i) {
                    int hgl = th * 8 + wv * 2 + i;
                    int wgl = tw * 16 + lw;
                    oaccb[((size_t)b * 108 + m) * HW + hgl * WW + wgl] =
                        f2bf(acc[mt][i][r] + bia);
                }
            }
        }
    }
}

// deformable conv MFMA + fused stats partials.  grid 1024 (4 blocks/CU).
__global__ __launch_bounds__(256, 4) void dcn_mfma(const ushort_t* __restrict__ xT,
                                                   const ushort_t* __restrict__ oaccb,
                                                   const ushort_t* __restrict__ wA,
                                                   float* __restrict__ out,
                                                   float* __restrict__ parts) {
    int blk = blockIdx.x;
    int xcd = blk & 7;
    int b = xcd >> 2;
    int quad = xcd & 3;
    int unit = blk >> 3;
    int g = unit >> 5;
    int tl = unit & 31;
    int th = quad * 4 + (tl >> 3);
    int tw = tl & 7;
    int t = threadIdx.x;
    int wv = t >> 6, lane = t & 63;
    int lw = lane & 15, kg = lane >> 4;

    __shared__ ushort_t colLDS[128 * 72];     // 18.4 KB
    __shared__ uint_t idxLDS[2][4][128];      // 4 KB (double-buffered)
    __shared__ float  wgtLDS[2][4][128];      // 4 KB
    __shared__ float  sumLDS[4][64];          // 1 KB
    __shared__ float  sqLDS[4][64];           // 1 KB

    const ushort_t* xTb = xT + (size_t)b * HW * 64;

    int p1 = t & 127;
    int h1 = th * 8 + (p1 >> 4);
    int w1 = tw * 16 + (p1 & 15);
    const ushort_t* ob_in = oaccb + (size_t)(b * 4 + g) * 27 * HW + h1 * WW + w1;

#define P1(KK, BUF)                                                               \
    if (t < 128) {                                                                \
        float dy = bfu(ob_in[(size_t)(2 * (KK)) * HW]);                           \
        float dx = bfu(ob_in[(size_t)(2 * (KK) + 1) * HW]);                       \
        float mk = 1.f / (1.f + expf(-bfu(ob_in[(size_t)(18 + (KK)) * HW])));     \
        float py = (float)h1 + (float)((KK) / 3 - 1) + dy;                        \
        float qx = (float)w1 + (float)((KK) % 3 - 1) + dx;                        \
        float y0f = floorf(py), x0f = floorf(qx);                                 \
        float ly = py - y0f, lx = qx - x0f;                                       \
        int y0 = (int)y0f, x0 = (int)x0f;                                         \
        int y1 = y0 + 1, x1 = x0 + 1;                                             \
        bool vy0 = (y0 >= 0) && (y0 < HH), vy1 = (y1 >= 0) && (y1 < HH);          \
        bool vx0 = (x0 >= 0) && (x0 < WW), vx1 = (x1 >= 0) && (x1 < WW);          \
        int yc0 = min(max(y0, 0), HH - 1), yc1 = min(max(y1, 0), HH - 1);         \
        int xc0 = min(max(x0, 0), WW - 1), xc1 = min(max(x1, 0), WW - 1);         \
        idxLDS[BUF][0][p1] = (uint_t)(yc0 * WW + xc0);                            \
        idxLDS[BUF][1][p1] = (uint_t)(yc0 * WW + xc1);                            \
        idxLDS[BUF][2][p1] = (uint_t)(yc1 * WW + xc0);                            \
        idxLDS[BUF][3][p1] = (uint_t)(yc1 * WW + xc1);                            \
        wgtLDS[BUF][0][p1] = (1.f - ly) * (1.f - lx) * mk * ((vy0 && vx0) ? 1.f : 0.f); \
        wgtLDS[BUF][1][p1] = (1.f - ly) * lx * mk * ((vy0 && vx1) ? 1.f : 0.f);   \
        wgtLDS[BUF][2][p1] = ly * (1.f - lx) * mk * ((vy1 && vx0) ? 1.f : 0.f);   \
        wgtLDS[BUF][3][p1] = ly * lx * mk * ((vy1 && vx1) ? 1.f : 0.f);           \
    }

    f32x4 acc[4][2];
#pragma unroll
    for (int mt = 0; mt < 4; ++mt)
#pragma unroll
        for (int i = 0; i < 2; ++i)
            acc[mt][i] = (f32x4){0.f, 0.f, 0.f, 0.f};

    const bf16x8* wAv = (const bf16x8*)wA + (size_t)g * 4608;

    P1(0, 0);
    __syncthreads();

    for (int k = 0; k < 9; ++k) {
        int cur = k & 1;
        int chunk = t & 7;
#pragma unroll
        for (int iter = 0; iter < 4; ++iter) {
            int p = iter * 32 + (t >> 3);
            uint_t i00 = idxLDS[cur][0][p], i01 = idxLDS[cur][1][p];
            uint_t i10 = idxLDS[cur][2][p], i11 = idxLDS[cur][3][p];
            float w00 = wgtLDS[cur][0][p], w01 = wgtLDS[cur][1][p];
            float w10 = wgtLDS[cur][2][p], w11 = wgtLDS[cur][3][p];
            uint4 u00 = *(const uint4*)(xTb + (size_t)i00 * 64 + chunk * 8);
            uint4 u01 = *(const uint4*)(xTb + (size_t)i01 * 64 + chunk * 8);
            uint4 u10 = *(const uint4*)(xTb + (size_t)i10 * 64 + chunk * 8);
            uint4 u11 = *(const uint4*)(xTb + (size_t)i11 * 64 + chunk * 8);
            uint4 res;
#define CMB(E) pack2(w00 * bflo(u00.E) + w01 * bflo(u01.E) + w10 * bflo(u10.E) + w11 * bflo(u11.E), \
                     w00 * bfhi(u00.E) + w01 * bfhi(u01.E) + w10 * bfhi(u10.E) + w11 * bfhi(u11.E))
            res.x = CMB(x);
            res.y = CMB(y);
            res.z = CMB(z);
            res.w = CMB(w);
#undef CMB
            *(uint4*)&colLDS[p * 72 + chunk * 8] = res;
        }
        __syncthreads();

        if (k < 8) { P1(k + 1, cur ^ 1); }

#pragma unroll
        for (int kt2 = 0; kt2 < 2; ++kt2) {
            int kt = k * 2 + kt2;
            bf16x8 bfrag[2];
#pragma unroll
            for (int i = 0; i < 2; ++i)
                bfrag[i] = *(const bf16x8*)
                    &colLDS[((wv * 2 + i) * 16 + lw) * 72 + (kt2 * 4 + kg) * 8];
            bf16x8 afrag[4];
#pragma unroll
            for (int mt = 0; mt < 4; ++mt)
                afrag[mt] = wAv[(kt * 4 + mt) * 64 + lane];
#pragma unroll
            for (int mt = 0; mt < 4; ++mt)
#pragma unroll
                for (int i = 0; i < 2; ++i)
                    acc[mt][i] = __builtin_amdgcn_mfma_f32_16x16x32_bf16(
                        afrag[mt], bfrag[i], acc[mt][i], 0, 0, 0);
        }
        __syncthreads();
    }
#undef P1

    int s1 = g >> 1, s2g = g & 1;
#pragma unroll
    for (int mt = 0; mt < 4; ++mt) {
#pragma unroll
        for (int i = 0; i < 2; ++i) {
            int p2 = (wv * 2 + i) * 16 + lw;
            int hg = th * 8 + (p2 >> 4);
            int wg = tw * 16 + (p2 & 15);
            float* op = out + ((size_t)b * 64 + mt * 16 + (kg << 2)) * 65536
                      + (size_t)(hg * 2 + s1) * 256 + (wg * 2 + s2g);
#pragma unroll
            for (int r = 0; r < 4; ++r)
                op[(size_t)r * 65536] = acc[mt][i][r];
        }
    }

#pragma unroll
    for (int mt = 0; mt < 4; ++mt) {
#pragma unroll
        for (int r = 0; r < 4; ++r) {
            float a0 = acc[mt][0][r], a1 = acc[mt][1][r];
            float s = a0 + a1;
            float s2 = a0 * a0 + a1 * a1;
#pragma unroll
            for (int m = 1; m < 16; m <<= 1) {
                s += __shfl_xor(s, m);
                s2 += __shfl_xor(s2, m);
            }
            if (lw == 0) {
                int ml = mt * 16 + (kg << 2) + r;
                sumLDS[wv][ml] = s;
                sqLDS[wv][ml] = s2;
            }
        }
    }
    __syncthreads();
    if (t < 128) {
        int o = t & 63;
        bool isq = t >= 64;
        float v = 0.f;
#pragma unroll
        for (int w2 = 0; w2 < 4; ++w2)
            v += isq ? sqLDS[w2][o] : sumLDS[w2][o];
        parts[(size_t)(isq ? 64 + o : o) * 1024 + blk] = v;
    }
}

// reduce 1024 per-block partials -> a/b per channel.  grid 64.
__global__ __launch_bounds__(256) void stats_reduce(const float* __restrict__ parts,
                                                    const float* __restrict__ gamma,
                                                    const float* __restrict__ beta,
                                                    float* __restrict__ ab) {
    int o = blockIdx.x;
    int t = threadIdx.x;
    float s = 0.f, s2 = 0.f;
    for (int i = t; i < 1024; i += 256) {
        s += parts[(size_t)o * 1024 + i];
        s2 += parts[(size_t)(64 + o) * 1024 + i];
    }
    __shared__ float red[512];
    red[t] = s;
    red[256 + t] = s2;
    __syncthreads();
#pragma unroll
    for (int m = 128; m >= 1; m >>= 1) {
        if (t < m) {
            red[t] += red[t + m];
            red[256 + t] += red[256 + t + m];
        }
        __syncthreads();
    }
    if (t == 0) {
        float mean = red[0] / NVALS;
        float var = red[256] / NVALS - mean * mean;
        var = fmaxf(var, 0.f);
        float a = gamma[o] * rsqrtf(var + 1e-5f);
        ab[o] = a;
        ab[64 + o] = beta[o] - mean * a;
    }
}

// normalize + relu, 8 floats/thread.  grid 4096.
__global__ __launch_bounds__(256) void norm_relu(float* __restrict__ out,
                                                 const float* __restrict__ ab) {
    size_t tid = (size_t)blockIdx.x * 256 + threadIdx.x;
    size_t base = tid * 8;
    int o = (int)((base >> 16) & 63);
    float a = ab[o], bb = ab[64 + o];
    float4* p = (float4*)(out + base);
    float4 v0 = p[0];
    float4 v1 = p[1];
    v0.x = fmaxf(fmaf(v0.x, a, bb), 0.f);
    v0.y = fmaxf(fmaf(v0.y, a, bb), 0.f);
    v0.z = fmaxf(fmaf(v0.z, a, bb), 0.f);
    v0.w = fmaxf(fmaf(v0.w, a, bb), 0.f);
    v1.x = fmaxf(fmaf(v1.x, a, bb), 0.f);
    v1.y = fmaxf(fmaf(v1.y, a, bb), 0.f);
    v1.z = fmaxf(fmaf(v1.z, a, bb), 0.f);
    v1.w = fmaxf(fmaf(v1.w, a, bb), 0.f);
    p[0] = v0;
    p[1] = v1;
}

extern "C" void kernel_launch(void* const* d_in, const int* in_sizes, int n_in,
                              void* d_out, int out_size, void* d_ws, size_t ws_size,
                              hipStream_t stream) {
    const float* x        = (const float*)d_in[0];
    const float* w_offset = (const float*)d_in[1];
    const float* b_offset = (const float*)d_in[2];
    const float* w_dcn    = (const float*)d_in[3];
    const float* gamma    = (const float*)d_in[4];
    const float* beta     = (const float*)d_in[5];
    float* out            = (float*)d_out;
    float* ws = (float*)d_ws;

    prep_all<<<1088, 256, 0, stream>>>(x, w_offset, b_offset, w_dcn, ws);
    conv_mfma<<<256, 256, 0, stream>>>((ushort_t*)(ws + XT), (ushort_t*)(ws + WACONV),
                                       ws + BIAS2, (ushort_t*)(ws + OACC));
    dcn_mfma<<<1024, 256, 0, stream>>>((ushort_t*)(ws + XT), (ushort_t*)(ws + OACC),
                                       (ushort_t*)(ws + WADCN), out, ws + PARTS);
    stats_reduce<<<64, 256, 0, stream>>>(ws + PARTS, gamma, beta, ws + STATS + 128);
    norm_relu<<<4096, 256, 0, stream>>>(out, ws + STATS + 128);
}